// Round 8
// baseline (5764.782 us; speedup 1.0000x reference)
//
#include <hip/hip_runtime.h>

// Problem constants
constexpr int B = 64, T = 1024, D = 128, H = 256;
// RNN partition: 16 batch-groups (GB=4 batches) x 16 blocks (16 units each).
// Block = 512 threads = 16 units x 32 k-lanes; 36 weight floats/thread.
constexpr int NG = 16;   // batch groups
constexpr int GB = 4;    // batches per group
constexpr int GK = 16;   // blocks per group
constexpr int UO = 16;   // hidden units owned per block

__device__ __forceinline__ float sigmoidf_(float v) {
    return 1.f / (1.f + __expf(-v));
}
__device__ __forceinline__ float tanhf_(float v) {
    float e2 = __expf(2.f * v);
    return 1.f - 2.f / (e2 + 1.f);
}
// XOR-swizzled index into a 256-float h row: k -> slot s=k>>2, phys slot
// s ^ ((s>>3)&7). Reads (b128 at slots 2kc, 2kc+1) spread 4-way max; writes
// (consecutive k per lane) 2-way max.
__device__ __forceinline__ int hidx(int bb, int k) {
    int s = k >> 2;
    s = s ^ ((s >> 3) & 7);
    return bb * 256 + s * 4 + (k & 3);
}

// ---------------- P1: per-(b,d) scan over t (prefetch-unrolled) ----------------
__global__ __launch_bounds__(64) void prep_scan(
    const float* __restrict__ x, const int* __restrict__ mask,
    const float* __restrict__ ts, const float* __restrict__ it0,
    float* __restrict__ ffill, float* __restrict__ idelta,
    float* __restrict__ mean, float* __restrict__ tdlv)
{
    const int b = blockIdx.x;
    const int d = blockIdx.y * 64 + threadIdx.x;
    float prev_x = 0.f, prev_td = 0.f, osum = 0.f, mcnt = 0.f;
    float prev_ts = it0[b];               // init_time is (1,B) -> flat[b]
    const int baseT = b * T;
    constexpr int U = 16;
    for (int t0 = 0; t0 < T; t0 += U) {
        float xv[U]; int mv[U]; float tsv[U];
        #pragma unroll
        for (int uu = 0; uu < U; ++uu) {
            const int idx = (baseT + t0 + uu) * D + d;
            xv[uu] = x[idx];
            mv[uu] = mask[idx];
        }
        #pragma unroll
        for (int uu = 0; uu < U; ++uu) tsv[uu] = ts[baseT + t0 + uu];
        #pragma unroll
        for (int uu = 0; uu < U; ++uu) {
            const float td = tsv[uu] - prev_ts;
            prev_ts = tsv[uu];
            const int idx = (baseT + t0 + uu) * D + d;
            if (!mv[uu]) { prev_x = xv[uu]; osum += xv[uu]; } else { mcnt += 1.f; }
            prev_td += td;
            ffill[idx]  = prev_x;
            idelta[idx] = prev_td;
            if (!mv[uu]) prev_td = 0.f;
            if (d == 0) tdlv[baseT + t0 + uu] = logf(fminf(fmaxf(td, 0.f), 1000.f));
        }
    }
    mean[b * D + d] = osum / fmaxf(mcnt, 1.f);
}

// ---------------- P2: imputation matvec ----------------
constexpr int ROWS = 64;   // (b,t) rows per block
__global__ __launch_bounds__(256) void fill_kernel(
    const float* __restrict__ x, const int* __restrict__ mask,
    const float* __restrict__ ffill, const float* __restrict__ idelta,
    const float* __restrict__ mean, const float* __restrict__ idw,
    const float* __restrict__ idb, float* __restrict__ xf)
{
    __shared__ float widw[128 * 129];   // padded: conflict-free
    __shared__ float ide[2][128];
    const int tid = threadIdx.x;
    for (int i = tid; i < 128 * 128; i += 256)
        widw[(i >> 7) * 129 + (i & 127)] = idw[i];
    __syncthreads();
    const int p = tid >> 7, d = tid & 127;
    const float bias = idb[d];
    const int row0 = blockIdx.x * ROWS;
    for (int r = 0; r < ROWS; r += 2) {
        const int rowp = row0 + r + p;    // b*T + t
        const int idx = rowp * D + d;
        ide[p][d] = fminf(fmaxf(idelta[idx] - 1.f, 0.f), 1000.f);
        __syncthreads();
        float acc = bias;
        #pragma unroll
        for (int k = 0; k < 128; ++k)
            acc = fmaf(ide[p][k], widw[d * 129 + k], acc);
        float fw = __expf(-fmaxf(acc, 0.f));
        float filled = ffill[idx] * fw + (1.f - fw) * mean[(rowp >> 10) * D + d];
        xf[idx] = mask[idx] ? filled : x[idx];
        __syncthreads();
    }
}

// ---------------- P3: persistent grouped GRU-D recurrence ----------------
// 16 groups x 16 blocks; block = 16 units x 32 k-lanes, 4 batches. Fence-free
// tagged 64-bit LLC exchange, parity double-buffered hdec (swizzled), one
// barrier per step. Reduce-scatter (m=16,8,4,2) leaves lane kc with item
// (kc>>1)&15 = bb*4+gate; lanes kc&7==0 publish batch kc>>3.
__global__ __launch_bounds__(512) void rnn_kernel(
    const float* __restrict__ xf, const float* __restrict__ tdlv,
    const float* __restrict__ w_ih, const float* __restrict__ w_hh,
    const float* __restrict__ b_ih, const float* __restrict__ b_hh,
    const float* __restrict__ hdw, const float* __restrict__ hdb,
    unsigned long long* __restrict__ hx, float* __restrict__ out)
{
    const int tid = threadIdx.x;
    const int g  = blockIdx.x & (NG - 1);   // batch group (same XCD mod 8)
    const int kb = blockIdx.x >> 4;         // owns units [kb*16, kb*16+16)
    const int u  = tid >> 5;                // 0..15 unit-local
    const int kc = tid & 31;                // 0..31 k-lane
    const int row = kb * UO + u;            // owned hidden unit
    const int b0 = g * GB;

    // Weight slices: w_hh k in [kc*8, kc*8+8), w_ih k in [kc*4, kc*4+4)
    float whr[8], whz[8], whn[8];
    #pragma unroll
    for (int j = 0; j < 8; ++j) {
        whr[j] = w_hh[(size_t)(row        ) * H + kc * 8 + j];
        whz[j] = w_hh[(size_t)(row +     H) * H + kc * 8 + j];
        whn[j] = w_hh[(size_t)(row + 2 * H) * H + kc * 8 + j];
    }
    float wir[4], wiz[4], win_[4];
    #pragma unroll
    for (int j = 0; j < 4; ++j) {
        wir[j]  = w_ih[(size_t)(row        ) * D + kc * 4 + j];
        wiz[j]  = w_ih[(size_t)(row +     H) * D + kc * 4 + j];
        win_[j] = w_ih[(size_t)(row + 2 * H) * D + kc * 4 + j];
    }
    const float br  = b_ih[row] + b_hh[row];
    const float bz  = b_ih[H + row] + b_hh[H + row];
    const float bnx = b_ih[2 * H + row];
    const float bnh = b_hh[2 * H + row];

    // Staging role: thread stages unit sk for batch pair pb
    const int sk = tid & 255;
    const int pb = tid >> 8;                // 0/1 -> batches {2pb, 2pb+1}
    const bool ownk = ((sk >> 4) == kb);
    const float hdwk = hdw[sk], hdbk = hdb[sk];
    const float hdwo = hdw[row], hdbo = hdb[row];
    const bool pub = ((kc & 7) == 0);       // publisher lanes: kc in {0,8,16,24}
    const int pbb = kc >> 3;                // published batch

    // 83968 B static LDS -> exactly 1 block/CU. Used: [0, 2048) floats
    // = 2 parities x 4 batches x 256 swizzled h values.
    __shared__ float hdec[20992];
    for (int i = tid; i < 2048; i += 512) hdec[i] = 0.f;   // h0 = 0
    __syncthreads();

    const float* tdlb = tdlv;

    for (int t = 0; t < T; ++t) {
        const int par = t & 1;

        // ---- (a) probe the 2 remote tag words early ----
        const bool need = (t > 0) && !ownk;
        const unsigned long long* slotp =
            hx + (size_t)((t - 1) & 1) * (B * H) + (size_t)(b0 + pb * 2) * H + sk;
        unsigned long long v0 = 0, v1 = 0;
        if (need) {
            v0 = __hip_atomic_load(slotp,     __ATOMIC_RELAXED, __HIP_MEMORY_SCOPE_AGENT);
            v1 = __hip_atomic_load(slotp + H, __ATOMIC_RELAXED, __HIP_MEMORY_SCOPE_AGENT);
        }

        // ---- (b) gi partials (independent of h) ----
        float acc[16];
        #pragma unroll
        for (int i = 0; i < 16; ++i) acc[i] = 0.f;
        #pragma unroll
        for (int bb = 0; bb < GB; ++bb) {
            float4 xq = *(const float4*)(xf + (size_t)((b0 + bb) * T + t) * D + kc * 4);
            float a0 = acc[bb * 4 + 0], a1 = acc[bb * 4 + 1], a2 = acc[bb * 4 + 2];
            a0 = fmaf(wir[0], xq.x, a0); a1 = fmaf(wiz[0], xq.x, a1); a2 = fmaf(win_[0], xq.x, a2);
            a0 = fmaf(wir[1], xq.y, a0); a1 = fmaf(wiz[1], xq.y, a1); a2 = fmaf(win_[1], xq.y, a2);
            a0 = fmaf(wir[2], xq.z, a0); a1 = fmaf(wiz[2], xq.z, a1); a2 = fmaf(win_[2], xq.z, a2);
            a0 = fmaf(wir[3], xq.w, a0); a1 = fmaf(wiz[3], xq.w, a1); a2 = fmaf(win_[3], xq.w, a2);
            acc[bb * 4 + 0] = a0; acc[bb * 4 + 1] = a1; acc[bb * 4 + 2] = a2;
        }
        // publisher's next-step decay input
        float tdn = 0.f;
        if (pub && t + 1 < T) tdn = tdlb[(b0 + pbb) * T + t + 1];

        // ---- (c) finish poll + stage decayed remote h into LDS ----
        if (need) {
            while (!(((unsigned)(v0 >> 32) == (unsigned)t) &&
                     ((unsigned)(v1 >> 32) == (unsigned)t))) {
                v0 = __hip_atomic_load(slotp,     __ATOMIC_RELAXED, __HIP_MEMORY_SCOPE_AGENT);
                v1 = __hip_atomic_load(slotp + H, __ATOMIC_RELAXED, __HIP_MEMORY_SCOPE_AGENT);
            }
            float td0 = tdlb[(b0 + pb * 2    ) * T + t];
            float td1 = tdlb[(b0 + pb * 2 + 1) * T + t];
            float dec0 = __expf(-fmaxf(td0 * hdwk + hdbk, 0.f));
            float dec1 = __expf(-fmaxf(td1 * hdwk + hdbk, 0.f));
            hdec[par * 1024 + hidx(pb * 2,     sk)] = __uint_as_float((unsigned)v0) * dec0;
            hdec[par * 1024 + hidx(pb * 2 + 1, sk)] = __uint_as_float((unsigned)v1) * dec1;
        }
        __syncthreads();

        // ---- (d) gh partials from swizzled LDS ----
        const int s0 = 2 * kc;
        const int p0 = s0 ^ ((s0 >> 3) & 7);
        const int p1 = p0 ^ 1;
        #pragma unroll
        for (int bb = 0; bb < GB; ++bb) {
            const float* base = &hdec[par * 1024 + bb * 256];
            float4 h0 = *(const float4*)(base + p0 * 4);
            float4 h1 = *(const float4*)(base + p1 * 4);
            float a0 = acc[bb * 4 + 0], a1 = acc[bb * 4 + 1], a3 = acc[bb * 4 + 3];
            a0 = fmaf(whr[0], h0.x, a0); a1 = fmaf(whz[0], h0.x, a1); a3 = fmaf(whn[0], h0.x, a3);
            a0 = fmaf(whr[1], h0.y, a0); a1 = fmaf(whz[1], h0.y, a1); a3 = fmaf(whn[1], h0.y, a3);
            a0 = fmaf(whr[2], h0.z, a0); a1 = fmaf(whz[2], h0.z, a1); a3 = fmaf(whn[2], h0.z, a3);
            a0 = fmaf(whr[3], h0.w, a0); a1 = fmaf(whz[3], h0.w, a1); a3 = fmaf(whn[3], h0.w, a3);
            a0 = fmaf(whr[4], h1.x, a0); a1 = fmaf(whz[4], h1.x, a1); a3 = fmaf(whn[4], h1.x, a3);
            a0 = fmaf(whr[5], h1.y, a0); a1 = fmaf(whz[5], h1.y, a1); a3 = fmaf(whn[5], h1.y, a3);
            a0 = fmaf(whr[6], h1.z, a0); a1 = fmaf(whz[6], h1.z, a1); a3 = fmaf(whn[6], h1.z, a3);
            a0 = fmaf(whr[7], h1.w, a0); a1 = fmaf(whz[7], h1.w, a1); a3 = fmaf(whn[7], h1.w, a3);
            acc[bb * 4 + 0] = a0; acc[bb * 4 + 1] = a1; acc[bb * 4 + 3] = a3;
        }

        // ---- (e) reduce-scatter over 32 lanes: lane kc ends with item (kc>>1)&15 ----
        #pragma unroll
        for (int m = 16; m >= 2; m >>= 1) {
            const bool sel = (kc & m);
            #pragma unroll
            for (int j = 0; j < m / 2; ++j) {
                float lo = acc[j], hi = acc[j + m / 2];
                float keep = sel ? hi : lo;
                float send = sel ? lo : hi;
                acc[j] = keep + __shfl_xor(send, m, 64);
            }
        }
        float vfin = acc[0] + __shfl_xor(acc[0], 1, 64);   // full 32-lane sum
        float zv  = __shfl_xor(vfin, 2, 64);               // gate z
        float nxv = __shfl_xor(vfin, 4, 64);               // gate nx
        float nhv = __shfl_xor(vfin, 6, 64);               // gate nh

        // ---- (f) publisher epilogue (kc in {0,8,16,24}; batch pbb) ----
        if (pub) {
            float hd = hdec[par * 1024 + hidx(pbb, row)];
            float r = sigmoidf_(vfin + br);
            float z = sigmoidf_(zv + bz);
            float n = tanhf_(nxv + bnx + r * (nhv + bnh));
            float hnew = (1.f - z) * n + z * hd;
            // publish to LLC first (tag = t+1)
            __hip_atomic_store(hx + (size_t)par * (B * H) + (size_t)(b0 + pbb) * H + row,
                               (((unsigned long long)(unsigned)(t + 1)) << 32) |
                               (unsigned long long)__float_as_uint(hnew),
                               __ATOMIC_RELAXED, __HIP_MEMORY_SCOPE_AGENT);
            // pre-stage own unit's decayed h for t+1
            if (t + 1 < T) {
                float dec = __expf(-fmaxf(tdn * hdwo + hdbo, 0.f));
                hdec[(par ^ 1) * 1024 + hidx(pbb, row)] = hnew * dec;
            }
            out[(size_t)((b0 + pbb) * T + t) * H + row] = hnew;
            if (t == T - 1)
                out[(size_t)B * T * H + (b0 + pbb) * H + row] = hnew;
        }
        // single barrier per step: parity buffering + the collective barrier
        // order all hdec writes before their reads (skew-1 proof as before).
    }
}

extern "C" void kernel_launch(void* const* d_in, const int* in_sizes, int n_in,
                              void* d_out, int out_size, void* d_ws, size_t ws_size,
                              hipStream_t stream) {
    (void)in_sizes; (void)n_in; (void)out_size; (void)ws_size;
    const float* x    = (const float*)d_in[0];
    const int*   mask = (const int*)d_in[1];
    const float* ts   = (const float*)d_in[2];
    const float* it0  = (const float*)d_in[3];
    const float* w_ih = (const float*)d_in[4];
    const float* w_hh = (const float*)d_in[5];
    const float* b_ih = (const float*)d_in[6];
    const float* b_hh = (const float*)d_in[7];
    const float* idw  = (const float*)d_in[8];
    const float* idb  = (const float*)d_in[9];
    const float* hdw  = (const float*)d_in[10];
    const float* hdb  = (const float*)d_in[11];
    float* out = (float*)d_out;

    // Workspace layout (bytes)
    char* ws = (char*)d_ws;
    float* xf   = (float*)(ws);                              // 33554432 B
    float* tdlv = (float*)(ws + 33554432);                   // 262144 B
    float* mean = (float*)(ws + 33816576);                   // 32768 B
    unsigned long long* hx = (unsigned long long*)(ws + 33849344); // 2*B*H u64

    // d_out used as scratch before the RNN overwrites it entirely:
    float* ffill  = out;
    float* idelta = out + (size_t)B * T * D;

    // zero tag words each launch (replay safety)
    hipMemsetAsync(hx, 0, (size_t)(2 * B * H) * 8, stream);

    prep_scan<<<dim3(B, 2), 64, 0, stream>>>(x, mask, ts, it0, ffill, idelta, mean, tdlv);
    fill_kernel<<<(B * T) / ROWS, 256, 0, stream>>>(x, mask, ffill, idelta, mean, idw, idb, xf);
    rnn_kernel<<<NG * GK, 512, 0, stream>>>(xf, tdlv, w_ih, w_hh, b_ih, b_hh, hdw, hdb,
                                            hx, out);
}

// Round 9
// 5324.001 us; speedup vs baseline: 1.0828x; 1.0828x over previous
//
#include <hip/hip_runtime.h>

// Problem constants
constexpr int B = 64, T = 1024, D = 128, H = 256;
// RNN partition: 16 batch-groups (GB=4) x 8 blocks (32 units each), grid 128.
// Block = 1024 threads = 32 units x 32 k-lanes; 36 weight floats/thread.
constexpr int NG = 16;   // batch groups
constexpr int GB = 4;    // batches per group
constexpr int GK = 8;    // blocks per group
constexpr int UO = 32;   // hidden units owned per block

__device__ __forceinline__ float sigmoidf_(float v) {
    return 1.f / (1.f + __expf(-v));
}
__device__ __forceinline__ float tanhf_(float v) {
    float e2 = __expf(2.f * v);
    return 1.f - 2.f / (e2 + 1.f);
}

// ---------------- P1: per-(b,d) scan over t (prefetch-unrolled) ----------------
__global__ __launch_bounds__(64) void prep_scan(
    const float* __restrict__ x, const int* __restrict__ mask,
    const float* __restrict__ ts, const float* __restrict__ it0,
    float* __restrict__ ffill, float* __restrict__ idelta,
    float* __restrict__ mean, float* __restrict__ tdlv)
{
    const int b = blockIdx.x;
    const int d = blockIdx.y * 64 + threadIdx.x;
    float prev_x = 0.f, prev_td = 0.f, osum = 0.f, mcnt = 0.f;
    float prev_ts = it0[b];               // init_time is (1,B) -> flat[b]
    const int baseT = b * T;
    constexpr int U = 16;
    for (int t0 = 0; t0 < T; t0 += U) {
        float xv[U]; int mv[U]; float tsv[U];
        #pragma unroll
        for (int uu = 0; uu < U; ++uu) {
            const int idx = (baseT + t0 + uu) * D + d;
            xv[uu] = x[idx];
            mv[uu] = mask[idx];
        }
        #pragma unroll
        for (int uu = 0; uu < U; ++uu) tsv[uu] = ts[baseT + t0 + uu];
        #pragma unroll
        for (int uu = 0; uu < U; ++uu) {
            const float td = tsv[uu] - prev_ts;
            prev_ts = tsv[uu];
            const int idx = (baseT + t0 + uu) * D + d;
            if (!mv[uu]) { prev_x = xv[uu]; osum += xv[uu]; } else { mcnt += 1.f; }
            prev_td += td;
            ffill[idx]  = prev_x;
            idelta[idx] = prev_td;
            if (!mv[uu]) prev_td = 0.f;
            if (d == 0) tdlv[baseT + t0 + uu] = logf(fminf(fmaxf(td, 0.f), 1000.f));
        }
    }
    mean[b * D + d] = osum / fmaxf(mcnt, 1.f);
}

// ---------------- P2: imputation matvec ----------------
constexpr int ROWS = 64;   // (b,t) rows per block
__global__ __launch_bounds__(256) void fill_kernel(
    const float* __restrict__ x, const int* __restrict__ mask,
    const float* __restrict__ ffill, const float* __restrict__ idelta,
    const float* __restrict__ mean, const float* __restrict__ idw,
    const float* __restrict__ idb, float* __restrict__ xf)
{
    __shared__ float widw[128 * 129];   // padded: conflict-free
    __shared__ float ide[2][128];
    const int tid = threadIdx.x;
    for (int i = tid; i < 128 * 128; i += 256)
        widw[(i >> 7) * 129 + (i & 127)] = idw[i];
    __syncthreads();
    const int p = tid >> 7, d = tid & 127;
    const float bias = idb[d];
    const int row0 = blockIdx.x * ROWS;
    for (int r = 0; r < ROWS; r += 2) {
        const int rowp = row0 + r + p;    // b*T + t
        const int idx = rowp * D + d;
        ide[p][d] = fminf(fmaxf(idelta[idx] - 1.f, 0.f), 1000.f);
        __syncthreads();
        float acc = bias;
        #pragma unroll
        for (int k = 0; k < 128; ++k)
            acc = fmaf(ide[p][k], widw[d * 129 + k], acc);
        float fw = __expf(-fmaxf(acc, 0.f));
        float filled = ffill[idx] * fw + (1.f - fw) * mean[(rowp >> 10) * D + d];
        xf[idx] = mask[idx] ? filled : x[idx];
        __syncthreads();
    }
}

// ---------------- P3: persistent grouped GRU-D recurrence ----------------
// 16 groups x 8 blocks; block = 32 units x 32 k-lanes, 4 batches. Fence-free
// tagged 64-bit LLC exchange (tag = step+1 | f32 bits), parity double-buffered
// hdec (chunk stride 10 floats -> 2-way bank aliasing = free), one barrier per
// step. Reduce-scatter over 32 kc lanes: lane kc ends with item kc>>1 =
// bb*4+gate; lanes kc&7==0 publish batch kc>>3. One tag slot per thread.
__global__ __launch_bounds__(1024) void rnn_kernel(
    const float* __restrict__ xf, const float* __restrict__ tdlv,
    const float* __restrict__ w_ih, const float* __restrict__ w_hh,
    const float* __restrict__ b_ih, const float* __restrict__ b_hh,
    const float* __restrict__ hdw, const float* __restrict__ hdb,
    unsigned long long* __restrict__ hx, float* __restrict__ out)
{
    const int tid = threadIdx.x;
    const int g  = blockIdx.x & (NG - 1);   // batch group (same XCD mod 8)
    const int kb = blockIdx.x >> 4;         // 0..7: owns units [kb*32, kb*32+32)
    const int u  = tid >> 5;                // 0..31 unit-local
    const int kc = tid & 31;                // 0..31 k-lane
    const int row = kb * UO + u;            // owned hidden unit
    const int b0 = g * GB;

    // Weight slices: w_hh k in [kc*8, kc*8+8), w_ih k in [kc*4, kc*4+4)
    float whr[8], whz[8], whn[8];
    #pragma unroll
    for (int j = 0; j < 8; ++j) {
        whr[j] = w_hh[(size_t)(row        ) * H + kc * 8 + j];
        whz[j] = w_hh[(size_t)(row +     H) * H + kc * 8 + j];
        whn[j] = w_hh[(size_t)(row + 2 * H) * H + kc * 8 + j];
    }
    float wir[4], wiz[4], win_[4];
    #pragma unroll
    for (int j = 0; j < 4; ++j) {
        wir[j]  = w_ih[(size_t)(row        ) * D + kc * 4 + j];
        wiz[j]  = w_ih[(size_t)(row +     H) * D + kc * 4 + j];
        win_[j] = w_ih[(size_t)(row + 2 * H) * D + kc * 4 + j];
    }
    const float br  = b_ih[row] + b_hh[row];
    const float bz  = b_ih[H + row] + b_hh[H + row];
    const float bnx = b_ih[2 * H + row];
    const float bnh = b_hh[2 * H + row];

    // Staging role: thread stages unit sk for batch sb (1 slot per thread)
    const int sk = tid & 255;
    const int sb = tid >> 8;                // 0..3
    const bool ownk = ((sk >> 5) == kb);
    const float hdwk = hdw[sk], hdbk = hdb[sk];
    const float hdwo = hdw[row], hdbo = hdb[row];
    const bool pub = ((kc & 7) == 0);       // publisher lanes: kc in {0,8,16,24}
    const int pbb = kc >> 3;                // published batch index

    // hdec: [par][bb][32 chunks x 10 floats] = 2*4*320 floats; padded to 84KB
    // to pin exactly 1 block/CU.
    __shared__ float hdec[21504];
    for (int i = tid; i < 2 * GB * 320; i += 1024) hdec[i] = 0.f;   // h0 = 0
    __syncthreads();

    for (int t = 0; t < T; ++t) {
        const int par = t & 1;

        // ---- (a) probe the remote tag word early (hide under gi) ----
        const bool need = (t > 0) && !ownk;
        const unsigned long long* slot =
            hx + (size_t)((t - 1) & 1) * (B * H) + (size_t)(b0 + sb) * H + sk;
        unsigned long long v = 0;
        if (need)
            v = __hip_atomic_load(slot, __ATOMIC_RELAXED, __HIP_MEMORY_SCOPE_AGENT);

        // ---- (b) gi partials (independent of h) ----
        float acc[16];
        #pragma unroll
        for (int i = 0; i < 16; ++i) acc[i] = 0.f;
        #pragma unroll
        for (int bb = 0; bb < GB; ++bb) {
            float4 xq = *(const float4*)(xf + (size_t)((b0 + bb) * T + t) * D + kc * 4);
            float a0 = 0.f, a1 = 0.f, a2 = 0.f;
            a0 = fmaf(wir[0], xq.x, a0); a1 = fmaf(wiz[0], xq.x, a1); a2 = fmaf(win_[0], xq.x, a2);
            a0 = fmaf(wir[1], xq.y, a0); a1 = fmaf(wiz[1], xq.y, a1); a2 = fmaf(win_[1], xq.y, a2);
            a0 = fmaf(wir[2], xq.z, a0); a1 = fmaf(wiz[2], xq.z, a1); a2 = fmaf(win_[2], xq.z, a2);
            a0 = fmaf(wir[3], xq.w, a0); a1 = fmaf(wiz[3], xq.w, a1); a2 = fmaf(win_[3], xq.w, a2);
            acc[bb * 4 + 0] = a0; acc[bb * 4 + 1] = a1; acc[bb * 4 + 2] = a2;
        }
        float tdn = 0.f;
        if (pub && t + 1 < T) tdn = tdlv[(b0 + pbb) * T + t + 1];

        // ---- (c) finish poll + stage decayed remote h into LDS ----
        if (need) {
            while ((unsigned)(v >> 32) != (unsigned)t)
                v = __hip_atomic_load(slot, __ATOMIC_RELAXED, __HIP_MEMORY_SCOPE_AGENT);
            float td = tdlv[(b0 + sb) * T + t];
            float dec = __expf(-fmaxf(td * hdwk + hdbk, 0.f));
            hdec[par * 1280 + sb * 320 + (sk >> 3) * 10 + (sk & 7)] =
                __uint_as_float((unsigned)v) * dec;
        }
        __syncthreads();

        // ---- (d) gh partials: chunk kc (8 floats) per batch via b64 reads ----
        #pragma unroll
        for (int bb = 0; bb < GB; ++bb) {
            const float* base = &hdec[par * 1280 + bb * 320 + kc * 10];
            float2 h0 = *(const float2*)(base);
            float2 h1 = *(const float2*)(base + 2);
            float2 h2 = *(const float2*)(base + 4);
            float2 h3 = *(const float2*)(base + 6);
            float a0 = acc[bb * 4 + 0], a1 = acc[bb * 4 + 1], a3 = acc[bb * 4 + 3];
            a0 = fmaf(whr[0], h0.x, a0); a1 = fmaf(whz[0], h0.x, a1); a3 = fmaf(whn[0], h0.x, a3);
            a0 = fmaf(whr[1], h0.y, a0); a1 = fmaf(whz[1], h0.y, a1); a3 = fmaf(whn[1], h0.y, a3);
            a0 = fmaf(whr[2], h1.x, a0); a1 = fmaf(whz[2], h1.x, a1); a3 = fmaf(whn[2], h1.x, a3);
            a0 = fmaf(whr[3], h1.y, a0); a1 = fmaf(whz[3], h1.y, a1); a3 = fmaf(whn[3], h1.y, a3);
            a0 = fmaf(whr[4], h2.x, a0); a1 = fmaf(whz[4], h2.x, a1); a3 = fmaf(whn[4], h2.x, a3);
            a0 = fmaf(whr[5], h2.y, a0); a1 = fmaf(whz[5], h2.y, a1); a3 = fmaf(whn[5], h2.y, a3);
            a0 = fmaf(whr[6], h3.x, a0); a1 = fmaf(whz[6], h3.x, a1); a3 = fmaf(whn[6], h3.x, a3);
            a0 = fmaf(whr[7], h3.y, a0); a1 = fmaf(whz[7], h3.y, a1); a3 = fmaf(whn[7], h3.y, a3);
            acc[bb * 4 + 0] = a0; acc[bb * 4 + 1] = a1; acc[bb * 4 + 3] = a3;
        }

        // ---- (e) reduce-scatter over 32 lanes (16 items); item(kc) = kc>>1 ----
        #pragma unroll
        for (int m = 16; m >= 2; m >>= 1) {
            const bool sel = (kc & m);
            #pragma unroll
            for (int j = 0; j < m / 2; ++j) {
                float lo = acc[j], hi = acc[j + m / 2];
                float keep = sel ? hi : lo;
                float send = sel ? lo : hi;
                acc[j] = keep + __shfl_xor(send, m, 64);
            }
        }
        float vfin = acc[0] + __shfl_xor(acc[0], 1, 64);   // full 32-lane sum
        float zv  = __shfl_xor(vfin, 2, 64);               // item +1 (z)
        float nxv = __shfl_xor(vfin, 4, 64);               // item +2 (nx)
        float nhv = __shfl_xor(vfin, 6, 64);               // item +3 (nh)

        // ---- (f) publisher epilogue (kc in {0,8,16,24}; batch pbb) ----
        if (pub) {
            float hd = hdec[par * 1280 + pbb * 320 + (row >> 3) * 10 + (row & 7)];
            float r = sigmoidf_(vfin + br);
            float z = sigmoidf_(zv + bz);
            float n = tanhf_(nxv + bnx + r * (nhv + bnh));
            float hnew = (1.f - z) * n + z * hd;
            // publish to LLC first (tag = t+1)
            __hip_atomic_store(hx + (size_t)par * (B * H) + (size_t)(b0 + pbb) * H + row,
                               (((unsigned long long)(unsigned)(t + 1)) << 32) |
                               (unsigned long long)__float_as_uint(hnew),
                               __ATOMIC_RELAXED, __HIP_MEMORY_SCOPE_AGENT);
            // pre-stage own unit's decayed h for t+1
            if (t + 1 < T) {
                float dec = __expf(-fmaxf(tdn * hdwo + hdbo, 0.f));
                hdec[(par ^ 1) * 1280 + pbb * 320 + (row >> 3) * 10 + (row & 7)] = hnew * dec;
            }
            out[(size_t)((b0 + pbb) * T + t) * H + row] = hnew;
            if (t == T - 1)
                out[(size_t)B * T * H + (b0 + pbb) * H + row] = hnew;
        }
        // single barrier per step: parity buffering + the collective barrier
        // order all hdec writes before their reads (2-barrier-distance proof).
    }
}

extern "C" void kernel_launch(void* const* d_in, const int* in_sizes, int n_in,
                              void* d_out, int out_size, void* d_ws, size_t ws_size,
                              hipStream_t stream) {
    (void)in_sizes; (void)n_in; (void)out_size; (void)ws_size;
    const float* x    = (const float*)d_in[0];
    const int*   mask = (const int*)d_in[1];
    const float* ts   = (const float*)d_in[2];
    const float* it0  = (const float*)d_in[3];
    const float* w_ih = (const float*)d_in[4];
    const float* w_hh = (const float*)d_in[5];
    const float* b_ih = (const float*)d_in[6];
    const float* b_hh = (const float*)d_in[7];
    const float* idw  = (const float*)d_in[8];
    const float* idb  = (const float*)d_in[9];
    const float* hdw  = (const float*)d_in[10];
    const float* hdb  = (const float*)d_in[11];
    float* out = (float*)d_out;

    // Workspace layout (bytes)
    char* ws = (char*)d_ws;
    float* xf   = (float*)(ws);                              // 33554432 B
    float* tdlv = (float*)(ws + 33554432);                   // 262144 B
    float* mean = (float*)(ws + 33816576);                   // 32768 B
    unsigned long long* hx = (unsigned long long*)(ws + 33849344); // 2*B*H u64

    // d_out used as scratch before the RNN overwrites it entirely:
    float* ffill  = out;
    float* idelta = out + (size_t)B * T * D;

    // zero tag words each launch (replay safety)
    hipMemsetAsync(hx, 0, (size_t)(2 * B * H) * 8, stream);

    prep_scan<<<dim3(B, 2), 64, 0, stream>>>(x, mask, ts, it0, ffill, idelta, mean, tdlv);
    fill_kernel<<<(B * T) / ROWS, 256, 0, stream>>>(x, mask, ffill, idelta, mean, idw, idb, xf);
    rnn_kernel<<<NG * GK, 1024, 0, stream>>>(xf, tdlv, w_ih, w_hh, b_ih, b_hh, hdw, hdb,
                                             hx, out);
}